// Round 5
// baseline (620.752 us; speedup 1.0000x reference)
//
#include <hip/hip_runtime.h>
#include <hip/hip_bf16.h>
#include <cstdint>

// Problem constants: B=64, T=512, E=256, H=128, 4H=512.
#define BB 64
#define TT 512
#define EE 256
#define HH 128
#define G4 512

typedef _Float16 half2_t __attribute__((ext_vector_type(2)));
typedef _Float16 f16x4 __attribute__((ext_vector_type(4)));
typedef _Float16 f16x8 __attribute__((ext_vector_type(8)));
typedef float f32x4 __attribute__((ext_vector_type(4)));

#define BC(x) __builtin_bit_cast(half2_t, x)

__device__ __forceinline__ float fdot2f(half2_t a, half2_t b, float c) {
#if defined(__has_builtin)
#if __has_builtin(__builtin_amdgcn_fdot2)
  return __builtin_amdgcn_fdot2(a, b, c, false);
#else
  return c + (float)a[0] * (float)b[0] + (float)a[1] * (float)b[1];
#endif
#else
  return c + (float)a[0] * (float)b[0] + (float)a[1] * (float)b[1];
#endif
}

__device__ __forceinline__ float rcp_(float x) { return __builtin_amdgcn_rcpf(x); }
__device__ __forceinline__ float tanh_(float x) {
  float ax = fabsf(x);
  float e = __expf(-2.f * ax);             // in (0,1], no overflow ever
  float r = (1.f - e) * rcp_(1.f + e);
  return copysignf(r, x);
}

__device__ __forceinline__ float readlane_f(float x, int lane) {
#if defined(__has_builtin)
#if __has_builtin(__builtin_amdgcn_readlane)
  return __builtin_bit_cast(float, __builtin_amdgcn_readlane(__builtin_bit_cast(int, x), lane));
#else
  return __shfl(x, lane);
#endif
#else
  return __shfl(x, lane);
#endif
}

// 64-lane sum via DPP (VALU pipe, not LDS pipe), broadcast via readlane(63).
#if defined(__has_builtin)
#if __has_builtin(__builtin_amdgcn_update_dpp)
#define HAVE_DPP 1
#endif
#endif

__device__ __forceinline__ float wave_sum64_bcast(float x) {
#ifdef HAVE_DPP
#define DPP_ADD(ctrl)                                                          \
  {                                                                            \
    int _t = __builtin_amdgcn_update_dpp(0, __builtin_bit_cast(int, x), ctrl,  \
                                         0xf, 0xf, true);                      \
    x += __builtin_bit_cast(float, _t);                                        \
  }
  DPP_ADD(0x111)  // row_shr:1
  DPP_ADD(0x112)  // row_shr:2
  DPP_ADD(0x114)  // row_shr:4
  DPP_ADD(0x118)  // row_shr:8
  DPP_ADD(0x142)  // row_bcast:15
  DPP_ADD(0x143)  // row_bcast:31
#undef DPP_ADD
  return readlane_f(x, 63);
#else
#pragma unroll
  for (int s = 1; s <= 32; s <<= 1) x += __shfl_xor(x, s);
  return x;
#endif
}

// ---------------------------------------------------------------------------
// Kernel A: trans = row-softmax(transition); W16 = (f16)W_ih
// ---------------------------------------------------------------------------
__global__ __launch_bounds__(128) void prep_kernel(
    const float* __restrict__ transition, const float* __restrict__ W_ih,
    float* __restrict__ trans, _Float16* __restrict__ W16) {
  const int bid = blockIdx.x, t = threadIdx.x;
  if (bid < 128) {
    __shared__ float red[2];
    float v = transition[bid * HH + t];
    float m = v;
#pragma unroll
    for (int s = 32; s >= 1; s >>= 1) m = fmaxf(m, __shfl_xor(m, s));
    if ((t & 63) == 0) red[t >> 6] = m;
    __syncthreads();
    m = fmaxf(red[0], red[1]);
    float e = __expf(v - m);
    float s = e;
#pragma unroll
    for (int k = 32; k >= 1; k >>= 1) s += __shfl_xor(s, k);
    __syncthreads();  // protect red before reuse
    if ((t & 63) == 0) red[t >> 6] = s;
    __syncthreads();
    trans[bid * HH + t] = e * rcp_(red[0] + red[1]);
  } else {
    const int base = (bid - 128) * 1024 + t * 8;  // 131072 total elems
    float4 v0 = *(const float4*)(W_ih + base);
    float4 v1 = *(const float4*)(W_ih + base + 4);
    f16x8 h;
    h[0] = (_Float16)v0.x; h[1] = (_Float16)v0.y;
    h[2] = (_Float16)v0.z; h[3] = (_Float16)v0.w;
    h[4] = (_Float16)v1.x; h[5] = (_Float16)v1.y;
    h[6] = (_Float16)v1.z; h[7] = (_Float16)v1.w;
    *(f16x8*)(W16 + base) = h;
  }
}

// ---------------------------------------------------------------------------
// Kernel B: precomp[m][j] = sum_e inputs[m][e]*W_ih[j][e] + b_ih[j] + b_hh[j]
// M=32768, N=512, K=256.  MFMA f16 16x16x32.  grid (512, 2) x 256 threads.
// ---------------------------------------------------------------------------
__global__ __launch_bounds__(256) void gemm_in(
    const float* __restrict__ A, const _Float16* __restrict__ W16,
    const float* __restrict__ b_ih, const float* __restrict__ b_hh,
    float* __restrict__ out) {
  __shared__ _Float16 As[64][264];  // K=256 + 8 pad (16B-aligned rows)
  const int t = threadIdx.x;
  const int m0 = blockIdx.x * 64;
  const int n0 = blockIdx.y * 256;
  {
    const int c4 = t & 63, r0 = t >> 6;
#pragma unroll
    for (int p = 0; p < 16; ++p) {
      const int row = r0 + 4 * p;
      float4 v = *(const float4*)(A + (size_t)(m0 + row) * EE + c4 * 4);
      f16x4 h;
      h[0] = (_Float16)v.x; h[1] = (_Float16)v.y;
      h[2] = (_Float16)v.z; h[3] = (_Float16)v.w;
      *(f16x4*)&As[row][c4 * 4] = h;
    }
  }
  __syncthreads();
  const int w = t >> 6, L = t & 63;
  const int lrow = L & 15, quad = L >> 4, lk = quad * 8;
  f32x4 acc[4][4] = {};
  const _Float16* Wbase = W16 + (size_t)(n0 + w * 64) * EE;
#pragma unroll
  for (int kc = 0; kc < 8; ++kc) {
    f16x8 a[4], bf[4];
#pragma unroll
    for (int mf = 0; mf < 4; ++mf)
      a[mf] = *(const f16x8*)&As[mf * 16 + lrow][kc * 32 + lk];
#pragma unroll
    for (int nf = 0; nf < 4; ++nf)
      bf[nf] = *(const f16x8*)(Wbase + (size_t)(nf * 16 + lrow) * EE + kc * 32 + lk);
#pragma unroll
    for (int mf = 0; mf < 4; ++mf)
#pragma unroll
      for (int nf = 0; nf < 4; ++nf)
        acc[mf][nf] = __builtin_amdgcn_mfma_f32_16x16x32_f16(a[mf], bf[nf], acc[mf][nf], 0, 0, 0);
  }
#pragma unroll
  for (int nf = 0; nf < 4; ++nf) {
    const int j = n0 + w * 64 + nf * 16 + lrow;  // C/D: col = lane&15
    const float bias = b_ih[j] + b_hh[j];
#pragma unroll
    for (int mf = 0; mf < 4; ++mf) {
#pragma unroll
      for (int r = 0; r < 4; ++r) {  // C/D: row = quad*4 + r
        const int m = m0 + mf * 16 + quad * 4 + r;
        out[(size_t)m * G4 + j] = acc[mf][nf][r] + bias;
      }
    }
  }
}

// ---------------------------------------------------------------------------
// Kernel C: fused LSTM + softmax + CRF forward.  One 256-thread (4-wave)
// block per batch.  Thread t owns unit j = t&127, gate rows {t, t+256}
// (gates g0 = t>>7 in {0,1} = i/f -> sigmoid; g0+2 in {2,3} = g/o) and CRF
// quarters {g0, g0+2} of column j.
// Why 4 waves: phase-1 broadcast LDS reads (h: 16 b128, E: 8 b128/wave)
// scale with WAVE count, not thread count — R4's 8-wave version issued 176
// LDS instr/step (the measured bottleneck); this issues ~104.
// Layouts act[g*128+j] / Spart[q*128+j] are gate-major: phase-1 writes are
// lane-consecutive (conflict-free), phase-3 reads are 8 b64 at 8B lane
// stride (2-way = free) — kills R4's 3.67M bank-conflict count.
// Global precomp prefetched in batches of 8 steps (vmcnt drain amortized).
// Phase 3 (wave 0, lane l owns units 2l,2l+1): cell, softmax via DPP
// wave-sum, CRF max-proxy recursion in registers, f16 h/E writes.
// ---------------------------------------------------------------------------
__global__ __launch_bounds__(256) void lstm_crf(
    const float* __restrict__ precomp, const float* __restrict__ Whh,
    const float* __restrict__ trans, const int* __restrict__ labels,
    float* __restrict__ out_b) {
  const int b = blockIdx.x, t = threadIdx.x;
  const int g0 = t >> 7;   // first gate (0=i, 1=f); second gate is g0+2
  const int j = t & 127;   // unit index

  __shared__ __align__(16) _Float16 h_lds[HH];
  __shared__ __align__(16) _Float16 E_lds[HH];
  __shared__ __align__(16) float act[G4];    // [gate][unit]
  __shared__ __align__(16) float Spart[G4];  // [quarter][unit]
  __shared__ int lab[TT];

  // --- one-time loads -------------------------------------------------------
  half2_t w0[64], w1[64];  // W_hh rows t and t+256 as f16 pairs
  {
    const float4* wr0 = (const float4*)(Whh + (size_t)t * HH);
    const float4* wr1 = (const float4*)(Whh + (size_t)(t + 256) * HH);
#pragma unroll
    for (int i = 0; i < 32; ++i) {
      float4 v = wr0[i];
      half2_t p0, p1;
      p0[0] = (_Float16)v.x; p0[1] = (_Float16)v.y;
      p1[0] = (_Float16)v.z; p1[1] = (_Float16)v.w;
      w0[2 * i] = p0; w0[2 * i + 1] = p1;
      float4 u = wr1[i];
      half2_t q0, q1;
      q0[0] = (_Float16)u.x; q0[1] = (_Float16)u.y;
      q1[0] = (_Float16)u.z; q1[1] = (_Float16)u.w;
      w1[2 * i] = q0; w1[2 * i + 1] = q1;
    }
  }
  // et0/et1: exp(trans[i][j]) for i in quarter g0 and quarter g0+2
  half2_t et0[16], et1[16];
#pragma unroll
  for (int a = 0; a < 16; ++a) {
    float e0 = __expf(trans[(g0 * 32 + 2 * a) * HH + j]);
    float e1 = __expf(trans[(g0 * 32 + 2 * a + 1) * HH + j]);
    half2_t h2; h2[0] = (_Float16)e0; h2[1] = (_Float16)e1;
    et0[a] = h2;
    float f0 = __expf(trans[((g0 + 2) * 32 + 2 * a) * HH + j]);
    float f1 = __expf(trans[((g0 + 2) * 32 + 2 * a + 1) * HH + j]);
    half2_t h3; h3[0] = (_Float16)f0; h3[1] = (_Float16)f1;
    et1[a] = h3;
  }
  lab[t] = labels[b * TT + t];
  lab[t + 256] = labels[b * TT + t + 256];
  if (t < HH) { h_lds[t] = (_Float16)0.f; E_lds[t] = (_Float16)0.f; }

  // wave-0 persistent state (units 2t, 2t+1)
  float tr0x = 0.f, tr0y = 0.f, tr127x = 0.f, tr127y = 0.f;
  if (t < 64) {
    float2 v0 = *(const float2*)(trans + 2 * t);
    float2 v1 = *(const float2*)(trans + 127 * HH + 2 * t);
    tr0x = v0.x; tr0y = v0.y; tr127x = v1.x; tr127y = v1.y;
  }
  float c0 = 0.f, c1 = 0.f, preA = 0.f, preB = 0.f, mused = 0.f, emit = 0.f;

  const float* pc0 = precomp + (size_t)b * TT * G4 + t;
  const float* pc1 = pc0 + 256;
  float cb0[8], cb1[8], nb0[8], nb1[8];
#pragma unroll
  for (int k = 0; k < 8; ++k) {
    cb0[k] = pc0[(size_t)k * G4];
    cb1[k] = pc1[(size_t)k * G4];
  }
  __syncthreads();

#pragma unroll 1
  for (int base = 0; base < TT; base += 8) {
    const bool more = (base + 8 < TT);
    if (more) {
#pragma unroll
      for (int k = 0; k < 8; ++k) {
        nb0[k] = pc0[(size_t)(base + 8 + k) * G4];
        nb1[k] = pc1[(size_t)(base + 8 + k) * G4];
      }
    }
#pragma unroll
    for (int k = 0; k < 8; ++k) {
      const int step = base + k;
      // --- phase 1: two gate-row dots (full K) + two CRF quarter dots ------
      float a00 = 0.f, a01 = 0.f, a10 = 0.f, a11 = 0.f;
      const float4* hv4 = (const float4*)h_lds;
#pragma unroll
      for (int kc = 0; kc < 16; ++kc) {
        float4 hb = hv4[kc];
        const half2_t hx = BC(hb.x), hy = BC(hb.y), hz = BC(hb.z), hw = BC(hb.w);
        a00 = fdot2f(w0[4 * kc + 0], hx, a00);
        a01 = fdot2f(w0[4 * kc + 1], hy, a01);
        a00 = fdot2f(w0[4 * kc + 2], hz, a00);
        a01 = fdot2f(w0[4 * kc + 3], hw, a01);
        a10 = fdot2f(w1[4 * kc + 0], hx, a10);
        a11 = fdot2f(w1[4 * kc + 1], hy, a11);
        a10 = fdot2f(w1[4 * kc + 2], hz, a10);
        a11 = fdot2f(w1[4 * kc + 3], hw, a11);
      }
      float s00 = 0.f, s01 = 0.f, s10 = 0.f, s11 = 0.f;
      const float4* e0v = (const float4*)E_lds + g0 * 4;
      const float4* e1v = (const float4*)E_lds + (g0 + 2) * 4;
#pragma unroll
      for (int ec = 0; ec < 4; ++ec) {
        float4 ea = e0v[ec];
        s00 = fdot2f(et0[4 * ec + 0], BC(ea.x), s00);
        s01 = fdot2f(et0[4 * ec + 1], BC(ea.y), s01);
        s00 = fdot2f(et0[4 * ec + 2], BC(ea.z), s00);
        s01 = fdot2f(et0[4 * ec + 3], BC(ea.w), s01);
        float4 eb = e1v[ec];
        s10 = fdot2f(et1[4 * ec + 0], BC(eb.x), s10);
        s11 = fdot2f(et1[4 * ec + 1], BC(eb.y), s11);
        s10 = fdot2f(et1[4 * ec + 2], BC(eb.z), s10);
        s11 = fdot2f(et1[4 * ec + 3], BC(eb.w), s11);
      }
      const float gate0 = cb0[k] + (a00 + a01);   // gate g0 in {i,f}: sigmoid
      const float gate1 = cb1[k] + (a10 + a11);   // gate g0+2 in {g,o}
      const float av0 = rcp_(1.f + __expf(-gate0));
      // gate1: tanh when g0==0 (gate 2 = g), sigmoid when g0==1 (gate 3 = o)
      const bool isg = (g0 == 0);
      const float yy = isg ? (-2.f * fabsf(gate1)) : (-gate1);
      const float exv = __expf(yy);
      const float num = isg ? (1.f - exv) : 1.f;
      float av1 = num * rcp_(1.f + exv);
      av1 = isg ? copysignf(av1, gate1) : av1;
      act[t] = av0;                 // [g0][j]    lane-consecutive
      act[t + 256] = av1;           // [g0+2][j]
      Spart[t] = s00 + s01;         // [q=g0][j]
      Spart[t + 256] = s10 + s11;   // [q=g0+2][j]
      __syncthreads();  // A
      // --- phase 3 (wave 0): cell, softmax, CRF, state writes --------------
      if (t < 64) {
        const float2* a2 = (const float2*)act;
        float2 I = a2[t], F = a2[64 + t], G = a2[128 + t], O = a2[192 + t];
        const float2* s2 = (const float2*)Spart;
        float2 Sq0 = s2[t], Sq1 = s2[64 + t], Sq2 = s2[128 + t], Sq3 = s2[192 + t];
        c0 = F.x * c0 + I.x * G.x;
        c1 = F.y * c1 + I.y * G.y;
        const float h0 = O.x * tanh_(c0), h1 = O.y * tanh_(c1);
        const float e0 = __expf(h0), e1 = __expf(h1);  // |h|<1: no max-sub
        const float denom = wave_sum64_bcast(e0 + e1);
        const float rinv = rcp_(denom);
        const float p0 = e0 * rinv, p1 = e1 * rinv;
        const float Sa = (Sq0.x + Sq1.x) + (Sq2.x + Sq3.x);
        const float Sb = (Sq0.y + Sq1.y) + (Sq2.y + Sq3.y);
        const float lgSa = __logf(Sa), lgSb = __logf(Sb);
        const float lgS0 = readlane_f(lgSa, 0);      // unit 0's log S
        const int lb = lab[step];
        const float Mnext = (step == 0) ? 0.f : (mused + lgS0);
        preA = p0 + ((step == 0) ? tr0x : (mused + lgSa));
        preB = p1 + ((step == 0) ? tr0y : (mused + lgSb));
        if (2 * t == lb) emit += p0;
        if (2 * t + 1 == lb) emit += p1;
        half2_t Eh;
        Eh[0] = (_Float16)__expf(preA - Mnext);  // bounded ~[0.37, 7.4]
        Eh[1] = (_Float16)__expf(preB - Mnext);
        *(half2_t*)&E_lds[2 * t] = Eh;
        half2_t Hh;
        Hh[0] = (_Float16)h0; Hh[1] = (_Float16)h1;
        *(half2_t*)&h_lds[2 * t] = Hh;
        mused = Mnext;
      }
      __syncthreads();  // C
    }
    if (more) {
#pragma unroll
      for (int k = 0; k < 8; ++k) { cb0[k] = nb0[k]; cb1[k] = nb1[k]; }
    }
  }
  // --- epilogue (wave 0): Ps = LSE(pre + trans[127]); out_b = Ps - emit ----
  if (t < 64) {
    float v0 = preA + tr127x, v1 = preB + tr127y;
    float m = fmaxf(v0, v1);
#pragma unroll
    for (int s = 1; s <= 32; s <<= 1) m = fmaxf(m, __shfl_xor(m, s));
    float ex = __expf(v0 - m) + __expf(v1 - m);
    float em = emit;
#pragma unroll
    for (int s = 1; s <= 32; s <<= 1) {
      ex += __shfl_xor(ex, s);
      em += __shfl_xor(em, s);
    }
    if (t == 0) out_b[b] = m + __logf(ex) - em;
  }
}

// ---------------------------------------------------------------------------
// Kernel D: total = sum_b out_b[b] - sum_{b,t<511} trans[l_t][l_{t+1}]
// ---------------------------------------------------------------------------
__global__ __launch_bounds__(512) void finalize_kernel(
    const float* __restrict__ trans, const int* __restrict__ labels,
    const float* __restrict__ out_b, float* __restrict__ d_out) {
  const int t = threadIdx.x;
  float a = 0.f;
  if (t < TT - 1) {
    for (int b = 0; b < BB; ++b) {
      const int l0 = labels[b * TT + t];
      const int l1 = labels[b * TT + t + 1];
      a += trans[l0 * HH + l1];
    }
  }
  float x = ((t < BB) ? out_b[t] : 0.f) - a;
  __shared__ float red[8];
#pragma unroll
  for (int s = 32; s >= 1; s >>= 1) x += __shfl_xor(x, s);
  if ((t & 63) == 0) red[t >> 6] = x;
  __syncthreads();
  if (t == 0) {
    float s = 0.f;
#pragma unroll
    for (int i = 0; i < 8; ++i) s += red[i];
    d_out[0] = s;
  }
}

// ---------------------------------------------------------------------------
extern "C" void kernel_launch(void* const* d_in, const int* in_sizes, int n_in,
                              void* d_out, int out_size, void* d_ws, size_t ws_size,
                              hipStream_t stream) {
  const float* inputs = (const float*)d_in[0];      // (64,512,256) f32
  const int* labels = (const int*)d_in[1];          // (64,512) i32
  const float* W_ih = (const float*)d_in[2];        // (512,256) f32
  const float* W_hh = (const float*)d_in[3];        // (512,128) f32
  const float* b_ih = (const float*)d_in[4];        // (512,) f32
  const float* b_hh = (const float*)d_in[5];        // (512,) f32
  const float* transition = (const float*)d_in[6];  // (128,128) f32

  char* ws = (char*)d_ws;
  float* precomp = (float*)ws;                           // 64 MiB
  float* trans = (float*)(ws + 67108864);                // 64 KiB
  _Float16* W16 = (_Float16*)(ws + 67108864 + 65536);    // 256 KiB
  float* out_b = (float*)(ws + 67108864 + 65536 + 262144);

  prep_kernel<<<256, 128, 0, stream>>>(transition, W_ih, trans, W16);
  gemm_in<<<dim3(512, 2), 256, 0, stream>>>(inputs, W16, b_ih, b_hh, precomp);
  lstm_crf<<<64, 256, 0, stream>>>(precomp, W_hh, trans, labels, out_b);
  finalize_kernel<<<1, 512, 0, stream>>>(trans, labels, out_b, (float*)d_out);
}